// Round 1
// baseline (327.549 us; speedup 1.0000x reference)
//
#include <hip/hip_runtime.h>
#include <hip/hip_bf16.h>

typedef __bf16 bf16_t;
typedef bf16_t bf16x8 __attribute__((ext_vector_type(8)));
typedef float  f32x4  __attribute__((ext_vector_type(4)));

constexpr int Bc  = 2;
constexpr int Nc  = 256;
constexpr int Dc  = 256;
constexpr int DHc = 256;
constexpr int BM  = 64;          // i-rows per block
constexpr int NIB = Nc / BM;     // 4 i-blocks per (b,j)

// ---------------- prep: K = x@Wk + bk, V = x@Wv + bv ----------------
__global__ void prep_kv(const float* __restrict__ x,
                        const float* __restrict__ Wk, const float* __restrict__ bk,
                        const float* __restrict__ Wv, const float* __restrict__ bv,
                        float* __restrict__ Kd, float* __restrict__ Vd) {
    constexpr int RPB = 4;                 // rows per block
    __shared__ float xs[RPB][Dc];
    int r0 = blockIdx.x * RPB;
    int h  = threadIdx.x;                  // 0..255 = output col
    for (int rr = 0; rr < RPB; ++rr)
        xs[rr][h] = x[(size_t)(r0 + rr) * Dc + h];
    __syncthreads();
    float bkv = bk[h], bvv = bv[h];
    float ka[RPB], va[RPB];
    #pragma unroll
    for (int rr = 0; rr < RPB; ++rr) { ka[rr] = bkv; va[rr] = bvv; }
    for (int d = 0; d < Dc; ++d) {
        float wk = Wk[(size_t)d * DHc + h];
        float wv = Wv[(size_t)d * DHc + h];
        #pragma unroll
        for (int rr = 0; rr < RPB; ++rr) {
            ka[rr] += xs[rr][d] * wk;
            va[rr] += xs[rr][d] * wv;
        }
    }
    #pragma unroll
    for (int rr = 0; rr < RPB; ++rr) {
        Kd[(size_t)(r0 + rr) * DHc + h] = ka[rr];
        Vd[(size_t)(r0 + rr) * DHc + h] = va[rr];
    }
}

// ---------------- prep: WqT[n][d] = (bf16) Wq[d][n] ----------------
__global__ void prep_wqt(const float* __restrict__ Wq, bf16_t* __restrict__ WqT) {
    int n = blockIdx.x;
    int d = threadIdx.x;
    WqT[(size_t)n * Dc + d] = (bf16_t)Wq[(size_t)d * DHc + n];
}

// ---------------- main fused kernel ----------------
// block = (b, j, i-block of 64); 256 threads = 4 waves.
// Wave w computes Q rows 0..63 x cols [64w, 64w+64) via 16x16x32 bf16 MFMA.
struct SMu {
    union {
        struct {
            bf16_t A[BM][Dc + 8];      // e tile, +8 bf16 pad (16B) per row
            bf16_t Bt[DHc][40];        // WqT k-slice: [n][k0..k0+32), pad to 40
        } g;
        float Q[BM][DHc + 4];          // Q tile (f32), +4 pad
    };
};

__global__ __launch_bounds__(256, 2)
void edge_attn(const float* __restrict__ e,
               const float* __restrict__ bq,
               const bf16_t* __restrict__ WqT,
               const float* __restrict__ Kd,
               const float* __restrict__ Vd,
               float* __restrict__ eout) {
    __shared__ SMu sm;
    __shared__ float s_kj[DHc], s_vj[DHc], s_bq[DHc];
    __shared__ float s_ri[BM][4], s_rj[BM][4];
    __shared__ float s_ai[BM], s_aj[BM];

    const int bid = blockIdx.x;
    const int b   = bid / (Nc * NIB);
    const int rem = bid % (Nc * NIB);
    const int j   = rem / NIB;
    const int i0  = (rem % NIB) * BM;
    const int tid = threadIdx.x;
    const int l   = tid & 63;
    const int w   = tid >> 6;
    const int lr  = l & 15;            // row (A) / col (B) within fragment
    const int lk  = (l >> 4) * 8;      // k offset within fragment

    // per-(b,j) vectors
    {
        size_t off = ((size_t)b * Nc + j) * DHc + tid;
        s_kj[tid] = Kd[off];
        s_vj[tid] = Vd[off];
        s_bq[tid] = bq[tid];
    }

    // ---- stage A tile: e[b, j, i0:i0+64, :] -> bf16 LDS ----
    const float4* e4 = reinterpret_cast<const float4*>(
        e + (((size_t)b * Nc + j) * Nc + i0) * Dc);
    #pragma unroll
    for (int q = 0; q < 16; ++q) {
        int f = tid + q * 256;          // float4 index, 0..4095
        float4 v = e4[f];
        int r = f >> 6;                 // row 0..63
        int c = (f & 63) * 4;           // col 0..252
        union { bf16_t h[4]; uint2 u; } p;
        p.h[0] = (bf16_t)v.x; p.h[1] = (bf16_t)v.y;
        p.h[2] = (bf16_t)v.z; p.h[3] = (bf16_t)v.w;
        *reinterpret_cast<uint2*>(&sm.g.A[r][c]) = p.u;
    }

    // ---- GEMM: Q = A @ WqT^T  (M=64, N=256/4 per wave, K=256) ----
    f32x4 acc[4][4] = {};
    for (int ks = 0; ks < Dc / 32; ++ks) {
        const int k0 = ks * 32;
        __syncthreads();                // prev reads of Bt done / A staged
        {   // stage Bt[n][0..32) = WqT[n][k0..k0+32)
            const uint4* src = reinterpret_cast<const uint4*>(
                WqT + (size_t)tid * Dc + k0);
            uint4* dst = reinterpret_cast<uint4*>(&sm.g.Bt[tid][0]);
            dst[0] = src[0]; dst[1] = src[1]; dst[2] = src[2]; dst[3] = src[3];
        }
        __syncthreads();
        bf16x8 a[4], bb[4];
        #pragma unroll
        for (int m = 0; m < 4; ++m)
            a[m] = *reinterpret_cast<const bf16x8*>(&sm.g.A[m * 16 + lr][k0 + lk]);
        #pragma unroll
        for (int n = 0; n < 4; ++n)
            bb[n] = *reinterpret_cast<const bf16x8*>(&sm.g.Bt[w * 64 + n * 16 + lr][lk]);
        #pragma unroll
        for (int m = 0; m < 4; ++m)
            #pragma unroll
            for (int n = 0; n < 4; ++n)
                acc[m][n] = __builtin_amdgcn_mfma_f32_16x16x32_bf16(
                    a[m], bb[n], acc[m][n], 0, 0, 0);
    }
    __syncthreads();   // GEMM done; union region now becomes Q

    // ---- write Q (+bq) to LDS: C/D layout col=lane&15, row=(lane>>4)*4+reg ----
    #pragma unroll
    for (int m = 0; m < 4; ++m) {
        int row0 = m * 16 + (l >> 4) * 4;
        #pragma unroll
        for (int n = 0; n < 4; ++n) {
            int col = w * 64 + n * 16 + lr;
            float bqv = s_bq[col];
            #pragma unroll
            for (int qq = 0; qq < 4; ++qq)
                sm.Q[row0 + qq][col] = acc[m][n][qq] + bqv;
        }
    }
    __syncthreads();

    // ---- dots: si = <Q[r], K[b,i0+r]>, sj = <Q[r], K[b,j]> ----
    {
        const int r = l;        // row 0..63
        const int p = w;        // col-quarter 0..3
        const float4* Krow = reinterpret_cast<const float4*>(
            Kd + (((size_t)b * Nc) + i0 + r) * DHc + p * 64);
        const float4* Qrow = reinterpret_cast<const float4*>(&sm.Q[r][p * 64]);
        const float4* Kj4  = reinterpret_cast<const float4*>(&s_kj[p * 64]);
        float si = 0.f, sj = 0.f;
        #pragma unroll
        for (int c4 = 0; c4 < 16; ++c4) {
            float4 qv = Qrow[c4];
            float4 ki = Krow[c4];
            float4 kj = Kj4[c4];
            si += qv.x * ki.x + qv.y * ki.y + qv.z * ki.z + qv.w * ki.w;
            sj += qv.x * kj.x + qv.y * kj.y + qv.z * kj.z + qv.w * kj.w;
        }
        s_ri[r][p] = si;
        s_rj[r][p] = sj;
    }
    __syncthreads();
    if (tid < BM) {
        float si = s_ri[tid][0] + s_ri[tid][1] + s_ri[tid][2] + s_ri[tid][3];
        float sj = s_rj[tid][0] + s_rj[tid][1] + s_rj[tid][2] + s_rj[tid][3];
        constexpr float scale = 0.0625f;      // 1/sqrt(DH)
        float ai = 1.f / (1.f + __expf((sj - si) * scale));
        s_ai[tid] = ai;
        s_aj[tid] = 1.f - ai;
    }
    __syncthreads();

    // ---- output: e_out[r,:] = ai[r]*V[b,i0+r,:] + aj[r]*V[b,j,:] ----
    {
        const int cg = (tid & 63) * 4;        // col group (float4)
        const int ro = tid >> 6;
        const float* Vb = Vd + ((size_t)b * Nc + i0) * DHc;
        float* ob = eout + (((size_t)b * Nc + j) * Nc + i0) * DHc;
        float4 vj = *reinterpret_cast<const float4*>(&s_vj[cg]);
        #pragma unroll
        for (int q = 0; q < 16; ++q) {
            int r = q * 4 + ro;
            float aiv = s_ai[r], ajv = s_aj[r];
            float4 vi = *reinterpret_cast<const float4*>(Vb + (size_t)r * DHc + cg);
            float4 o;
            o.x = aiv * vi.x + ajv * vj.x;
            o.y = aiv * vi.y + ajv * vj.y;
            o.z = aiv * vi.z + ajv * vj.z;
            o.w = aiv * vi.w + ajv * vj.w;
            *reinterpret_cast<float4*>(ob + (size_t)r * DHc + cg) = o;
        }
    }
}

extern "C" void kernel_launch(void* const* d_in, const int* in_sizes, int n_in,
                              void* d_out, int out_size, void* d_ws, size_t ws_size,
                              hipStream_t stream) {
    const float* x  = (const float*)d_in[0];
    const float* e  = (const float*)d_in[1];
    const float* Wq = (const float*)d_in[2];
    const float* bq = (const float*)d_in[3];
    const float* Wk = (const float*)d_in[4];
    const float* bk = (const float*)d_in[5];
    const float* Wv = (const float*)d_in[6];
    const float* bv = (const float*)d_in[7];
    float* out = (float*)d_out;

    float*  Kd  = (float*)d_ws;
    float*  Vd  = Kd + (size_t)Bc * Nc * DHc;
    bf16_t* WqT = (bf16_t*)(Vd + (size_t)Bc * Nc * DHc);

    // output 0: x passthrough
    hipMemcpyAsync(out, x, (size_t)Bc * Nc * Dc * sizeof(float),
                   hipMemcpyDeviceToDevice, stream);

    prep_kv<<<Bc * Nc / 4, 256, 0, stream>>>(x, Wk, bk, Wv, bv, Kd, Vd);
    prep_wqt<<<DHc, Dc, 0, stream>>>(Wq, WqT);
    edge_attn<<<Bc * Nc * NIB, 256, 0, stream>>>(
        e, bq, WqT, Kd, Vd, out + (size_t)Bc * Nc * Dc);
}

// Round 2
// 306.617 us; speedup vs baseline: 1.0683x; 1.0683x over previous
//
#include <hip/hip_runtime.h>
#include <hip/hip_bf16.h>

constexpr int Bc  = 2;
constexpr int Nc  = 256;
constexpr int Dc  = 256;
constexpr int DHc = 256;
constexpr int BM  = 64;          // i-rows per block in edge kernel
constexpr int NIB = Nc / BM;     // 4 i-blocks per (b,j)

// ---------------- prep: K,V = x@W + b;  G = scale * K @ Wq^T;  cc = scale * <bq, K_row> ----
// G[i,dd] = scale * sum_h K[i,h] * Wq[dd,h]   (so edge score si = <e_row, G_i> + cc_i, pre-scaled)
__global__ __launch_bounds__(256)
void prep_gvc(const float* __restrict__ x,
              const float* __restrict__ Wq, const float* __restrict__ bq,
              const float* __restrict__ Wk, const float* __restrict__ bk,
              const float* __restrict__ Wv, const float* __restrict__ bv,
              float* __restrict__ G, float* __restrict__ V, float* __restrict__ cc) {
    constexpr int RPB = 4;
    constexpr float scale = 0.0625f;    // 1/sqrt(DH)
    __shared__ float xs[RPB][Dc];
    __shared__ float ks[RPB][DHc];
    const int r0 = blockIdx.x * RPB;
    const int dd = threadIdx.x;

    #pragma unroll
    for (int rr = 0; rr < RPB; ++rr)
        xs[rr][dd] = x[(size_t)(r0 + rr) * Dc + dd];
    __syncthreads();

    // K rows (to LDS) and V rows (to global), coalesced weight reads
    float ka[RPB], va[RPB];
    {
        float bkv = bk[dd], bvv = bv[dd];
        #pragma unroll
        for (int rr = 0; rr < RPB; ++rr) { ka[rr] = bkv; va[rr] = bvv; }
    }
    #pragma unroll 4
    for (int d0 = 0; d0 < Dc; ++d0) {
        float wk = Wk[(size_t)d0 * DHc + dd];
        float wv = Wv[(size_t)d0 * DHc + dd];
        #pragma unroll
        for (int rr = 0; rr < RPB; ++rr) {
            ka[rr] += xs[rr][d0] * wk;
            va[rr] += xs[rr][d0] * wv;
        }
    }
    #pragma unroll
    for (int rr = 0; rr < RPB; ++rr) {
        ks[rr][dd] = ka[rr];
        V[(size_t)(r0 + rr) * DHc + dd] = va[rr];
    }
    __syncthreads();

    // G rows: per-thread stream of Wq row dd (L1-cached lines, 16x reuse)
    float ga[RPB] = {};
    #pragma unroll 8
    for (int h = 0; h < DHc; ++h) {
        float wq = Wq[(size_t)dd * DHc + h];
        #pragma unroll
        for (int rr = 0; rr < RPB; ++rr) ga[rr] += ks[rr][h] * wq;
    }
    #pragma unroll
    for (int rr = 0; rr < RPB; ++rr)
        G[(size_t)(r0 + rr) * Dc + dd] = ga[rr] * scale;

    // cc[row] = scale * <bq, K_row>
    {
        int rr = dd >> 6, l = dd & 63;
        float p = 0.f;
        #pragma unroll
        for (int k = 0; k < 4; ++k) p += ks[rr][l + 64 * k] * bq[l + 64 * k];
        #pragma unroll
        for (int m = 1; m < 64; m <<= 1) p += __shfl_xor(p, m, 64);
        if (l == 0) cc[r0 + rr] = p * scale;
    }
}

// ---------------- main: stream e, two dots vs G, sigmoid, V-combine ----------------
// block = (b, j, i-block of 64); 4 waves; wave w owns i in [i0+16w, i0+16w+16)
__global__ __launch_bounds__(256)
void edge_main(const float* __restrict__ e,
               const float* __restrict__ G,
               const float* __restrict__ V,
               const float* __restrict__ cc,
               float* __restrict__ eout) {
    const int bid = blockIdx.x;
    const int b   = bid / (Nc * NIB);
    const int rem = bid % (Nc * NIB);
    const int j   = rem / NIB;
    const int i0  = (rem % NIB) * BM;
    const int tid = threadIdx.x;
    const int l   = tid & 63;
    const int w   = tid >> 6;

    const size_t nbase = (size_t)b * Nc;
    // hoisted per-(b,j) values: each lane keeps its float4 chunk
    const float4 gj = *reinterpret_cast<const float4*>(G + (nbase + j) * Dc + l * 4);
    const float4 vj = *reinterpret_cast<const float4*>(V + (nbase + j) * DHc + l * 4);
    const float  cj = cc[nbase + j];

    const int ibase = i0 + w * 16;
    const float4* erow = reinterpret_cast<const float4*>(
        e + (((size_t)b * Nc + j) * Nc + ibase) * Dc) + l;
    const float4* Grow = reinterpret_cast<const float4*>(G + (nbase + ibase) * Dc) + l;
    const float4* Vrow = reinterpret_cast<const float4*>(V + (nbase + ibase) * DHc) + l;
    float4* orow = reinterpret_cast<float4*>(
        eout + (((size_t)b * Nc + j) * Nc + ibase) * Dc) + l;
    const float* ccp = cc + nbase + ibase;

    #pragma unroll 4
    for (int t = 0; t < 16; ++t) {
        float4 ev = erow[(size_t)t * 64];
        float4 gi = Grow[(size_t)t * 64];
        float si = ev.x * gi.x + ev.y * gi.y + ev.z * gi.z + ev.w * gi.w;
        float sj = ev.x * gj.x + ev.y * gj.y + ev.z * gj.z + ev.w * gj.w;
        #pragma unroll
        for (int m = 1; m < 64; m <<= 1) {
            si += __shfl_xor(si, m, 64);
            sj += __shfl_xor(sj, m, 64);
        }
        si += ccp[t];
        sj += cj;
        float ai = 1.f / (1.f + __expf(sj - si));   // scores pre-scaled by 1/16
        float aj = 1.f - ai;
        float4 vi = Vrow[(size_t)t * 64];
        float4 o;
        o.x = ai * vi.x + aj * vj.x;
        o.y = ai * vi.y + aj * vj.y;
        o.z = ai * vi.z + aj * vj.z;
        o.w = ai * vi.w + aj * vj.w;
        orow[(size_t)t * 64] = o;
    }
}

extern "C" void kernel_launch(void* const* d_in, const int* in_sizes, int n_in,
                              void* d_out, int out_size, void* d_ws, size_t ws_size,
                              hipStream_t stream) {
    const float* x  = (const float*)d_in[0];
    const float* e  = (const float*)d_in[1];
    const float* Wq = (const float*)d_in[2];
    const float* bq = (const float*)d_in[3];
    const float* Wk = (const float*)d_in[4];
    const float* bk = (const float*)d_in[5];
    const float* Wv = (const float*)d_in[6];
    const float* bv = (const float*)d_in[7];
    float* out = (float*)d_out;

    float* G  = (float*)d_ws;                       // [B*N, D]
    float* V  = G + (size_t)Bc * Nc * Dc;           // [B*N, DH]
    float* cc = V + (size_t)Bc * Nc * DHc;          // [B*N]

    // output 0: x passthrough
    hipMemcpyAsync(out, x, (size_t)Bc * Nc * Dc * sizeof(float),
                   hipMemcpyDeviceToDevice, stream);

    prep_gvc<<<Bc * Nc / 4, 256, 0, stream>>>(x, Wq, bq, Wk, bk, Wv, bv, G, V, cc);
    edge_main<<<Bc * Nc * NIB, 256, 0, stream>>>(
        e, G, V, cc, out + (size_t)Bc * Nc * Dc);
}

// Round 4
// 295.006 us; speedup vs baseline: 1.1103x; 1.0394x over previous
//
#include <hip/hip_runtime.h>
#include <hip/hip_bf16.h>

typedef float nt4 __attribute__((ext_vector_type(4)));

constexpr int Bc  = 2;
constexpr int Nc  = 256;
constexpr int Dc  = 256;
constexpr int DHc = 256;
constexpr int BM  = 64;          // i-rows per block in edge kernel
constexpr int NIB = Nc / BM;     // 4 i-blocks per (b,j)

// ---------------- prep: K,V = x@W + b;  G = scale * K @ Wq^T;  cc = scale * <bq, K_row> ----
__global__ __launch_bounds__(256)
void prep_gvc(const float* __restrict__ x,
              const float* __restrict__ Wq, const float* __restrict__ bq,
              const float* __restrict__ Wk, const float* __restrict__ bk,
              const float* __restrict__ Wv, const float* __restrict__ bv,
              float* __restrict__ G, float* __restrict__ V, float* __restrict__ cc) {
    constexpr int RPB = 4;
    constexpr float scale = 0.0625f;    // 1/sqrt(DH)
    __shared__ float xs[RPB][Dc];
    __shared__ float ks[RPB][DHc];
    const int r0 = blockIdx.x * RPB;
    const int dd = threadIdx.x;

    #pragma unroll
    for (int rr = 0; rr < RPB; ++rr)
        xs[rr][dd] = x[(size_t)(r0 + rr) * Dc + dd];
    __syncthreads();

    float ka[RPB], va[RPB];
    {
        float bkv = bk[dd], bvv = bv[dd];
        #pragma unroll
        for (int rr = 0; rr < RPB; ++rr) { ka[rr] = bkv; va[rr] = bvv; }
    }
    #pragma unroll 4
    for (int d0 = 0; d0 < Dc; ++d0) {
        float wk = Wk[(size_t)d0 * DHc + dd];
        float wv = Wv[(size_t)d0 * DHc + dd];
        #pragma unroll
        for (int rr = 0; rr < RPB; ++rr) {
            ka[rr] += xs[rr][d0] * wk;
            va[rr] += xs[rr][d0] * wv;
        }
    }
    #pragma unroll
    for (int rr = 0; rr < RPB; ++rr) {
        ks[rr][dd] = ka[rr];
        V[(size_t)(r0 + rr) * DHc + dd] = va[rr];
    }
    __syncthreads();

    float ga[RPB] = {};
    #pragma unroll 8
    for (int h = 0; h < DHc; ++h) {
        float wq = Wq[(size_t)dd * DHc + h];
        #pragma unroll
        for (int rr = 0; rr < RPB; ++rr) ga[rr] += ks[rr][h] * wq;
    }
    #pragma unroll
    for (int rr = 0; rr < RPB; ++rr)
        G[(size_t)(r0 + rr) * Dc + dd] = ga[rr] * scale;

    {
        int rr = dd >> 6, l = dd & 63;
        float p = 0.f;
        #pragma unroll
        for (int k = 0; k < 4; ++k) p += ks[rr][l + 64 * k] * bq[l + 64 * k];
        #pragma unroll
        for (int m = 1; m < 64; m <<= 1) p += __shfl_xor(p, m, 64);
        if (l == 0) cc[r0 + rr] = p * scale;
    }
}

// ---------------- x passthrough as a kernel (avoid SDMA memcpy node in graph) ----
__global__ __launch_bounds__(256)
void copy_x(const float4* __restrict__ in, float4* __restrict__ out) {
    int i = blockIdx.x * 256 + threadIdx.x;
    out[i] = in[i];
}

// ---------------- main: stream e, two dots vs G, sigmoid, V-combine ----------------
// block = (b, j, i-block of 64); 4 waves; wave w owns rows [i0+16w, i0+16w+16)
// Within a wave: 4 groups of 16 lanes; group g handles row (batch*4 + g);
// lane covers float4 col c4 + 16k, k=0..3. Reduce = 4 shfl_xor stages.
__global__ __launch_bounds__(256)
void edge_main(const float* __restrict__ e,
               const float* __restrict__ G,
               const float* __restrict__ V,
               const float* __restrict__ cc,
               float* __restrict__ eout) {
    const int bid = blockIdx.x;
    const int b   = bid / (Nc * NIB);
    const int rem = bid % (Nc * NIB);
    const int j   = rem / NIB;
    const int i0  = (rem % NIB) * BM;
    const int tid = threadIdx.x;
    const int l   = tid & 63;
    const int w   = tid >> 6;
    const int g   = l >> 4;          // row-in-batch
    const int c4  = l & 15;          // float4 col base

    const size_t nbase = (size_t)b * Nc;
    const float4* G4 = reinterpret_cast<const float4*>(G);
    const float4* V4 = reinterpret_cast<const float4*>(V);

    float4 gj[4], vj[4];
    #pragma unroll
    for (int k = 0; k < 4; ++k) {
        gj[k] = G4[(nbase + j) * 64 + c4 + 16 * k];
        vj[k] = V4[(nbase + j) * 64 + c4 + 16 * k];
    }
    const float cj = cc[nbase + j];

    const int rbase = i0 + w * 16;    // wave's first row
    const float4* e4 = reinterpret_cast<const float4*>(e) +
                       (((size_t)b * Nc + j) * Nc + rbase) * 64;
    float4* o4 = reinterpret_cast<float4*>(eout) +
                 (((size_t)b * Nc + j) * Nc + rbase) * 64;
    const float4* Gi = G4 + (nbase + rbase) * 64;
    const float4* Vi = V4 + (nbase + rbase) * 64;
    const float*  ccp = cc + nbase + rbase;

    // prologue: batch 0 loads
    float4 ev[4], gi[4];
    #pragma unroll
    for (int k = 0; k < 4; ++k) {
        ev[k] = e4[(size_t)g * 64 + c4 + 16 * k];
        gi[k] = Gi[(size_t)g * 64 + c4 + 16 * k];
    }

    #pragma unroll
    for (int t = 0; t < 4; ++t) {
        const int r = t * 4 + g;
        // issue next batch's loads + this batch's V loads up front
        float4 nev[4], ngi[4], vi[4];
        if (t < 3) {
            #pragma unroll
            for (int k = 0; k < 4; ++k) {
                nev[k] = e4[(size_t)(r + 4) * 64 + c4 + 16 * k];
                ngi[k] = Gi[(size_t)(r + 4) * 64 + c4 + 16 * k];
            }
        }
        #pragma unroll
        for (int k = 0; k < 4; ++k)
            vi[k] = Vi[(size_t)r * 64 + c4 + 16 * k];

        float si = 0.f, sj = 0.f;
        #pragma unroll
        for (int k = 0; k < 4; ++k) {
            si += ev[k].x * gi[k].x + ev[k].y * gi[k].y + ev[k].z * gi[k].z + ev[k].w * gi[k].w;
            sj += ev[k].x * gj[k].x + ev[k].y * gj[k].y + ev[k].z * gj[k].z + ev[k].w * gj[k].w;
        }
        #pragma unroll
        for (int m = 1; m < 16; m <<= 1) {
            si += __shfl_xor(si, m, 64);
            sj += __shfl_xor(sj, m, 64);
        }
        si += ccp[r];
        sj += cj;
        float ai = 1.f / (1.f + __expf(sj - si));   // scores pre-scaled by 1/16
        float aj = 1.f - ai;

        #pragma unroll
        for (int k = 0; k < 4; ++k) {
            nt4 o;
            o.x = ai * vi[k].x + aj * vj[k].x;
            o.y = ai * vi[k].y + aj * vj[k].y;
            o.z = ai * vi[k].z + aj * vj[k].z;
            o.w = ai * vi[k].w + aj * vj[k].w;
            __builtin_nontemporal_store(
                o, reinterpret_cast<nt4*>(&o4[(size_t)r * 64 + c4 + 16 * k]));
        }
        #pragma unroll
        for (int k = 0; k < 4; ++k) { ev[k] = nev[k]; gi[k] = ngi[k]; }
    }
}

extern "C" void kernel_launch(void* const* d_in, const int* in_sizes, int n_in,
                              void* d_out, int out_size, void* d_ws, size_t ws_size,
                              hipStream_t stream) {
    const float* x  = (const float*)d_in[0];
    const float* e  = (const float*)d_in[1];
    const float* Wq = (const float*)d_in[2];
    const float* bq = (const float*)d_in[3];
    const float* Wk = (const float*)d_in[4];
    const float* bk = (const float*)d_in[5];
    const float* Wv = (const float*)d_in[6];
    const float* bv = (const float*)d_in[7];
    float* out = (float*)d_out;

    float* G  = (float*)d_ws;                       // [B*N, D]
    float* V  = G + (size_t)Bc * Nc * Dc;           // [B*N, DH]
    float* cc = V + (size_t)Bc * Nc * DHc;          // [B*N]

    prep_gvc<<<Bc * Nc / 4, 256, 0, stream>>>(x, Wq, bq, Wk, bk, Wv, bv, G, V, cc);
    edge_main<<<Bc * Nc * NIB, 256, 0, stream>>>(
        e, G, V, cc, out + (size_t)Bc * Nc * Dc);
    copy_x<<<(Bc * Nc * Dc / 4) / 256, 256, 0, stream>>>(
        (const float4*)x, (float4*)out);
}

// Round 6
// 288.047 us; speedup vs baseline: 1.1371x; 1.0242x over previous
//
#include <hip/hip_runtime.h>
#include <hip/hip_bf16.h>

typedef float nt4 __attribute__((ext_vector_type(4)));

constexpr int Bc  = 2;
constexpr int Nc  = 256;
constexpr int Dc  = 256;
constexpr int DHc = 256;

// ---------------- prep: K,V = x@W + b;  G = scale * K @ Wq^T;  cc = scale * <bq, K_row> ----
__global__ __launch_bounds__(256)
void prep_gvc(const float* __restrict__ x,
              const float* __restrict__ Wq, const float* __restrict__ bq,
              const float* __restrict__ Wk, const float* __restrict__ bk,
              const float* __restrict__ Wv, const float* __restrict__ bv,
              float* __restrict__ G, float* __restrict__ V, float* __restrict__ cc) {
    constexpr int RPB = 4;
    constexpr float scale = 0.0625f;    // 1/sqrt(DH)
    __shared__ float xs[RPB][Dc];
    __shared__ float ks[RPB][DHc];
    const int r0 = blockIdx.x * RPB;
    const int dd = threadIdx.x;

    #pragma unroll
    for (int rr = 0; rr < RPB; ++rr)
        xs[rr][dd] = x[(size_t)(r0 + rr) * Dc + dd];
    __syncthreads();

    float ka[RPB], va[RPB];
    {
        float bkv = bk[dd], bvv = bv[dd];
        #pragma unroll
        for (int rr = 0; rr < RPB; ++rr) { ka[rr] = bkv; va[rr] = bvv; }
    }
    #pragma unroll 4
    for (int d0 = 0; d0 < Dc; ++d0) {
        float wk = Wk[(size_t)d0 * DHc + dd];
        float wv = Wv[(size_t)d0 * DHc + dd];
        #pragma unroll
        for (int rr = 0; rr < RPB; ++rr) {
            ka[rr] += xs[rr][d0] * wk;
            va[rr] += xs[rr][d0] * wv;
        }
    }
    #pragma unroll
    for (int rr = 0; rr < RPB; ++rr) {
        ks[rr][dd] = ka[rr];
        V[(size_t)(r0 + rr) * DHc + dd] = va[rr];
    }
    __syncthreads();

    float ga[RPB] = {};
    #pragma unroll 8
    for (int h = 0; h < DHc; ++h) {
        float wq = Wq[(size_t)dd * DHc + h];
        #pragma unroll
        for (int rr = 0; rr < RPB; ++rr) ga[rr] += ks[rr][h] * wq;
    }
    #pragma unroll
    for (int rr = 0; rr < RPB; ++rr)
        G[(size_t)(r0 + rr) * Dc + dd] = ga[rr] * scale;

    {
        int rr = dd >> 6, l = dd & 63;
        float p = 0.f;
        #pragma unroll
        for (int k = 0; k < 4; ++k) p += ks[rr][l + 64 * k] * bq[l + 64 * k];
        #pragma unroll
        for (int m = 1; m < 64; m <<= 1) p += __shfl_xor(p, m, 64);
        if (l == 0) cc[r0 + rr] = p * scale;
    }
}

// ---------------- x passthrough as a kernel ----------------
__global__ __launch_bounds__(256)
void copy_x(const float4* __restrict__ in, float4* __restrict__ out) {
    int i = blockIdx.x * 256 + threadIdx.x;
    out[i] = in[i];
}

// ---------------- main: straight-line, 4 rows per wave, 16 rows per block ----
// block -> (b, j, i0 = 16-row slab); wave w, group g (16 lanes) owns row
// i = i0 + 4w + g; lane covers float4 cols {c4, c4+16, c4+32, c4+48}.
// All loads issued up front (e first: HBM; G/V: L2-hot), one 4-stage reduce,
// sigmoid, combine, NT store. No loop => nothing forces an early vmcnt drain.
__global__ __launch_bounds__(256)
void edge_main(const float* __restrict__ e,
               const float* __restrict__ G,
               const float* __restrict__ V,
               const float* __restrict__ cc,
               float* __restrict__ eout) {
    const int bid = blockIdx.x;
    const int b   = bid >> 12;            // / (256*16)
    const int rem = bid & 4095;
    const int j   = rem >> 4;
    const int i0  = (rem & 15) << 4;
    const int tid = threadIdx.x;
    const int l   = tid & 63;
    const int w   = tid >> 6;
    const int g   = l >> 4;
    const int c4  = l & 15;
    const int i   = i0 + w * 4 + g;

    const size_t nb = (size_t)b * Nc;
    const float4* G4 = reinterpret_cast<const float4*>(G);
    const float4* V4 = reinterpret_cast<const float4*>(V);
    const float4* e4 = reinterpret_cast<const float4*>(e) +
                       (((size_t)b * Nc + j) * Nc + i) * 64;
    float4* o4 = reinterpret_cast<float4*>(eout) +
                 (((size_t)b * Nc + j) * Nc + i) * 64;

    // e row chunks first (HBM latency)
    float4 ev0 = e4[c4], ev1 = e4[c4 + 16], ev2 = e4[c4 + 32], ev3 = e4[c4 + 48];

    const float4* Gi = G4 + (nb + i) * 64;
    const float4* Gj = G4 + (nb + j) * 64;
    const float4* Vi = V4 + (nb + i) * 64;
    const float4* Vj = V4 + (nb + j) * 64;
    float4 gi0 = Gi[c4], gi1 = Gi[c4 + 16], gi2 = Gi[c4 + 32], gi3 = Gi[c4 + 48];
    float4 gj0 = Gj[c4], gj1 = Gj[c4 + 16], gj2 = Gj[c4 + 32], gj3 = Gj[c4 + 48];
    float4 vi0 = Vi[c4], vi1 = Vi[c4 + 16], vi2 = Vi[c4 + 32], vi3 = Vi[c4 + 48];
    float4 vj0 = Vj[c4], vj1 = Vj[c4 + 16], vj2 = Vj[c4 + 32], vj3 = Vj[c4 + 48];
    const float ci = cc[nb + i];
    const float cj = cc[nb + j];

    float si, sj;
    {
        float a, bdot;
        a  = ev0.x * gi0.x + ev0.y * gi0.y + ev0.z * gi0.z + ev0.w * gi0.w;
        a += ev1.x * gi1.x + ev1.y * gi1.y + ev1.z * gi1.z + ev1.w * gi1.w;
        a += ev2.x * gi2.x + ev2.y * gi2.y + ev2.z * gi2.z + ev2.w * gi2.w;
        a += ev3.x * gi3.x + ev3.y * gi3.y + ev3.z * gi3.z + ev3.w * gi3.w;
        bdot  = ev0.x * gj0.x + ev0.y * gj0.y + ev0.z * gj0.z + ev0.w * gj0.w;
        bdot += ev1.x * gj1.x + ev1.y * gj1.y + ev1.z * gj1.z + ev1.w * gj1.w;
        bdot += ev2.x * gj2.x + ev2.y * gj2.y + ev2.z * gj2.z + ev2.w * gj2.w;
        bdot += ev3.x * gj3.x + ev3.y * gj3.y + ev3.z * gj3.z + ev3.w * gj3.w;
        si = a; sj = bdot;
    }
    #pragma unroll
    for (int m = 1; m < 16; m <<= 1) {
        si += __shfl_xor(si, m, 64);
        sj += __shfl_xor(sj, m, 64);
    }
    si += ci;
    sj += cj;
    const float ai = 1.f / (1.f + __expf(sj - si));   // scores pre-scaled by 1/16
    const float aj = 1.f - ai;

    nt4 o;
    #define EMIT(VI, VJ, OFF)                                   \
        o.x = ai * VI.x + aj * VJ.x;                            \
        o.y = ai * VI.y + aj * VJ.y;                            \
        o.z = ai * VI.z + aj * VJ.z;                            \
        o.w = ai * VI.w + aj * VJ.w;                            \
        __builtin_nontemporal_store(o, reinterpret_cast<nt4*>(&o4[OFF]));
    EMIT(vi0, vj0, c4)
    EMIT(vi1, vj1, c4 + 16)
    EMIT(vi2, vj2, c4 + 32)
    EMIT(vi3, vj3, c4 + 48)
    #undef EMIT
}

extern "C" void kernel_launch(void* const* d_in, const int* in_sizes, int n_in,
                              void* d_out, int out_size, void* d_ws, size_t ws_size,
                              hipStream_t stream) {
    const float* x  = (const float*)d_in[0];
    const float* e  = (const float*)d_in[1];
    const float* Wq = (const float*)d_in[2];
    const float* bq = (const float*)d_in[3];
    const float* Wk = (const float*)d_in[4];
    const float* bk = (const float*)d_in[5];
    const float* Wv = (const float*)d_in[6];
    const float* bv = (const float*)d_in[7];
    float* out = (float*)d_out;

    float* G  = (float*)d_ws;                       // [B*N, D]
    float* V  = G + (size_t)Bc * Nc * Dc;           // [B*N, DH]
    float* cc = V + (size_t)Bc * Nc * DHc;          // [B*N]

    prep_gvc<<<Bc * Nc / 4, 256, 0, stream>>>(x, Wq, bq, Wk, bk, Wv, bv, G, V, cc);
    edge_main<<<Bc * Nc * Nc / 16, 256, 0, stream>>>(
        e, G, V, cc, out + (size_t)Bc * Nc * Dc);
    copy_x<<<(Bc * Nc * Dc / 4) / 256, 256, 0, stream>>>(
        (const float4*)x, (float4*)out);
}